// Round 6
// baseline (121.623 us; speedup 1.0000x reference)
//
#include <hip/hip_runtime.h>
#include <math.h>

#define Lc 4096
#define Hc 1024
#define Bc 4
#define NNc 32

typedef __attribute__((ext_vector_type(8))) short s8v;
typedef __attribute__((ext_vector_type(4))) float f4v;

// swizzled element index for [64][64] bf16 matrix (rows 128B): XOR 16B slot by row&7
#define SWB(r, e) ((((r) << 6) + (e)) ^ (((r) & 7) << 3))

__device__ inline unsigned short bf16_rne(float x) {
    unsigned u = __float_as_uint(x);
    unsigned r = (u + 0x7FFFu + ((u >> 16) & 1u)) >> 16;
    return (unsigned short)r;
}
__device__ inline void split2(float x, unsigned short* h, unsigned short* l) {
    unsigned short hb = bf16_rne(x);
    *h = hb;
    float hf = __uint_as_float(((unsigned)hb) << 16);
    *l = bf16_rne(x - hf);
}

// t1: x [B][L][H] fp32 -> per-(b,h) 16KB blocks: hi bf16[4096], lo bf16[4096]
__global__ __launch_bounds__(256) void split_transpose(const float* __restrict__ src,
                                                       unsigned short* __restrict__ dst) {
    __shared__ float tile[64][65];
    int b  = blockIdx.z;
    int h0 = blockIdx.x * 64;
    int l0 = blockIdx.y * 64;
    const float* s = src + (size_t)b * Lc * Hc;
    int tid = threadIdx.x;
#pragma unroll
    for (int it = 0; it < 4; it++) {
        int idx = tid + 256 * it;
        int r = idx >> 4, c4 = idx & 15;            // r = l-row, c4 = h-quad
        float4 v = *(const float4*)(s + (size_t)(l0 + r) * Hc + (h0 + 4 * c4));
        tile[r][4 * c4 + 0] = v.x;
        tile[r][4 * c4 + 1] = v.y;
        tile[r][4 * c4 + 2] = v.z;
        tile[r][4 * c4 + 3] = v.w;
    }
    __syncthreads();
#pragma unroll
    for (int it = 0; it < 8; it++) {
        int hh = it * 8 + (tid >> 5);               // h within tile
        int p  = tid & 31;                          // l-pair within tile
        float v0 = tile[2 * p + 0][hh];
        float v1 = tile[2 * p + 1][hh];
        unsigned short h0b, l0b, h1b, l1b;
        split2(v0, &h0b, &l0b);
        split2(v1, &h1b, &l1b);
        unsigned hi = (unsigned)h0b | ((unsigned)h1b << 16);
        unsigned lo = (unsigned)l0b | ((unsigned)l1b << 16);
        unsigned short* base = dst + ((size_t)(b * Hc + h0 + hh)) * 8192;
        *(unsigned*)(base + (l0 + 2 * p))        = hi;
        *(unsigned*)(base + 4096 + (l0 + 2 * p)) = lo;
    }
}

// Batched 64x64-tile transpose, float4 global accesses (yT -> out).
__global__ __launch_bounds__(256) void transpose_v4(const float* __restrict__ src,
                                                    float* __restrict__ dst,
                                                    int R, int C) {
    __shared__ float tile[64][65];
    int b  = blockIdx.z;
    int c0 = blockIdx.x * 64;
    int r0 = blockIdx.y * 64;
    const float* s = src + (size_t)b * R * C;
    float*       d = dst + (size_t)b * R * C;
    int tid = threadIdx.x;
#pragma unroll
    for (int it = 0; it < 4; it++) {
        int idx = tid + 256 * it;
        int r = idx >> 4, c4 = idx & 15;
        float4 v = *(const float4*)(s + (size_t)(r0 + r) * C + (c0 + 4 * c4));
        tile[r][4 * c4 + 0] = v.x;
        tile[r][4 * c4 + 1] = v.y;
        tile[r][4 * c4 + 2] = v.z;
        tile[r][4 * c4 + 3] = v.w;
    }
    __syncthreads();
#pragma unroll
    for (int it = 0; it < 4; it++) {
        int idx = tid + 256 * it;
        int cc = idx >> 4, r4 = idx & 15;
        f4v v;
        v.x = tile[4 * r4 + 0][cc];
        v.y = tile[4 * r4 + 1][cc];
        v.z = tile[4 * r4 + 2][cc];
        v.w = tile[4 * r4 + 3][cc];
        __builtin_nontemporal_store(v, (f4v*)(d + (size_t)(c0 + cc) * R + (r0 + 4 * r4)));
    }
}

#define MFMA(a, b, c) __builtin_amdgcn_mfma_f32_16x16x32_bf16((a), (b), (c), 0, 0, 0)

// One block per h; 4 batches. ws holds x hi/lo bf16 planes per (b,h) 16KB block;
// yT fp32 overwrites the same block (streamed out via LDS staging, nontemporal).
__global__ __launch_bounds__(256, 4) void s4d_mfma4(
    unsigned short* __restrict__ wsp,
    const float* __restrict__ log_dt,
    const float* __restrict__ log_A_real,
    const float* __restrict__ A_imag,
    const float* __restrict__ Cmat,
    const float* __restrict__ Dvec)
{
    __shared__ __align__(16) unsigned short WtH[4096];   // S = X*Wrev (hi)
    __shared__ __align__(16) unsigned short WpH[4096];   // carry powers (hi)
    __shared__ float Sscan[64 * 65];   // [mode-comp][chunk]; Kpart scratch; Y staging
    __shared__ float Ktap[64];
    __shared__ float cAr[NNc], cAi[NNc], c2R[NNc], c2I[NNc], cWSr[NNc], cWSi[NNc];

    const int tid = threadIdx.x;
    const int h   = blockIdx.x;
    const int w   = tid >> 6;
    const int l   = tid & 63;
    const int l15 = l & 15;
    const int grp = l >> 4;
    const int rowoff = (16 * w + l15) * 64;

    // early X frag load for b=0 (hides under table generation)
    s8v xh0, xh1, xl0, xl1;
    {
        const unsigned short* xb = wsp + (size_t)h * 8192;
        xh0 = *(const s8v*)(xb + rowoff + 8 * grp);
        xh1 = *(const s8v*)(xb + rowoff + 32 + 8 * grp);
        xl0 = *(const s8v*)(xb + 4096 + rowoff + 8 * grp);
        xl1 = *(const s8v*)(xb + 4096 + rowoff + 32 + 8 * grp);
    }

    // ---- per-mode constants (PRECISE: w^64 errors compound x63 in the scan) ----
    if (tid < NNc) {
        int n = tid;
        float dtv = expf(log_dt[h]);
        float Ar = -expf(log_A_real[h * NNc + n]);
        float Ai = A_imag[h * NNc + n];
        float ar = Ar * dtv, ai = Ai * dtv;
        cAr[n] = ar; cAi[n] = ai;
        float er = expf(ar), sn, cs;
        sincosf(ai, &sn, &cs);
        float numr = er * cs - 1.f, numi = er * sn;
        float inv = 1.f / (Ar * Ar + Ai * Ai);
        float fr = (numr * Ar + numi * Ai) * inv;
        float fi = (numi * Ar - numr * Ai) * inv;
        float Ccr = Cmat[(h * NNc + n) * 2 + 0];
        float Cci = Cmat[(h * NNc + n) * 2 + 1];
        c2R[n] = 2.f * (Ccr * fr - Cci * fi);
        c2I[n] = 2.f * (Ccr * fi + Cci * fr);
        float e64 = expf(64.f * ar), s64, c64;
        sincosf(64.f * ai, &s64, &c64);
        cWSr[n] = e64 * c64; cWSi[n] = e64 * s64;   // w^64
    }
    __syncthreads();

    // ---- Kpart (into Sscan scratch) + Wt + Wp generation (fast intrinsics) ----
    {
        int p = tid >> 2, q = tid & 3;
        float acc = 0.f;
#pragma unroll
        for (int i = 0; i < 8; i++) {
            int n = 8 * q + i;
            float fp = (float)p;
            float e = __expf(cAr[n] * fp);
            float sn = __sinf(cAi[n] * fp), cs = __cosf(cAi[n] * fp);
            acc += e * (c2R[n] * cs - c2I[n] * sn);
        }
        Sscan[p * 4 + q] = acc;
    }
#pragma unroll
    for (int m = 0; m < 2; m++) {
        int u = tid + 256 * m;
        int r = u >> 3, jc = u & 7;
        {   // Wt row r = out mode-comp: w_n^{63-j} (hi only)
            int n = r >> 1, im = r & 1;
            s8v hv;
#pragma unroll
            for (int i = 0; i < 8; i++) {
                float p = (float)(63 - (jc * 8 + i));
                float e = __expf(cAr[n] * p);
                float sn = __sinf(cAi[n] * p), cs = __cosf(cAi[n] * p);
                hv[i] = (short)bf16_rne(e * (im ? sn : cs));
            }
            *(s8v*)&WtH[SWB(r, jc * 8)] = hv;
        }
        {   // Wp row r = t: col c: Re(w^{t+1}) / -Im(w^{t+1})  (hi only)
            float p = (float)(r + 1);
            s8v hv;
#pragma unroll
            for (int i = 0; i < 8; i++) {
                int c = jc * 8 + i;
                int n = c >> 1;
                float e = __expf(cAr[n] * p);
                float sn = __sinf(cAi[n] * p), cs = __cosf(cAi[n] * p);
                hv[i] = (short)bf16_rne(e * ((c & 1) ? -sn : cs));
            }
            *(s8v*)&WpH[SWB(r, jc * 8)] = hv;
        }
    }
    __syncthreads();

    if (tid < 64) {
        float k = Sscan[tid * 4] + Sscan[tid * 4 + 1] + Sscan[tid * 4 + 2] + Sscan[tid * 4 + 3];
        if (tid == 0) k += Dvec[h];
        Ktap[tid] = k;
    }
    __syncthreads();

    // ---- Toeplitz B-fragments: batch-invariant -> registers (8 x s8v) ----
    s8v tf[4][2];
#pragma unroll
    for (int tj = 0; tj < 4; tj++) {
        int row = tj * 16 + l15;
#pragma unroll
        for (int hf = 0; hf < 2; hf++) {
            int kb = 32 * hf + 8 * grp;
            s8v v;
#pragma unroll
            for (int i = 0; i < 8; i++) {
                int idx = row - kb - i;
                int ic = idx < 0 ? 0 : idx;
                float kv = Ktap[ic];
                v[i] = (short)bf16_rne(idx < 0 ? 0.f : kv);
            }
            tf[tj][hf] = v;
        }
    }

    // ---- batch loop ----
#pragma unroll
    for (int b = 0; b < Bc; b++) {
        // prefetch next batch's X fragments
        s8v nh0, nh1, nl0, nl1;
        if (b < Bc - 1) {
            const unsigned short* xb = wsp + (size_t)((b + 1) * Hc + h) * 8192;
            nh0 = *(const s8v*)(xb + rowoff + 8 * grp);
            nh1 = *(const s8v*)(xb + rowoff + 32 + 8 * grp);
            nl0 = *(const s8v*)(xb + 4096 + rowoff + 8 * grp);
            nl1 = *(const s8v*)(xb + 4096 + rowoff + 32 + 8 * grp);
        }

        // Phase 1: S = X * Wrev. D rows = chunk s, cols = mode-comp m.
        f4v acc[4];
#pragma unroll
        for (int tj = 0; tj < 4; tj++) {
            int row = tj * 16 + l15;
            int i0 = SWB(row, 8 * grp);
            int i1 = SWB(row, 32 + 8 * grp);
            s8v bh0 = *(const s8v*)&WtH[i0];
            s8v bh1 = *(const s8v*)&WtH[i1];
            f4v a = {0.f, 0.f, 0.f, 0.f};
            a = MFMA(xh0, bh0, a);
            a = MFMA(xh1, bh1, a);
            a = MFMA(xl0, bh0, a);
            a = MFMA(xl1, bh1, a);
            acc[tj] = a;
        }
        // store S transposed: Sscan[m][s]
#pragma unroll
        for (int tj = 0; tj < 4; tj++) {
#pragma unroll
            for (int r2 = 0; r2 < 4; r2++) {
                Sscan[(tj * 16 + l15) * 65 + 16 * w + 4 * grp + r2] = acc[tj][r2];
            }
        }
        __syncthreads();   // (a)

        // ---- wave-parallel Kogge-Stone scan: wave w owns modes 8w..8w+7, lane = chunk ----
        {
            float Pr[8], Pi[8], qr[8], qi[8];
#pragma unroll
            for (int i = 0; i < 8; i++) {
                int m0 = (16 * w + 2 * i) * 65;
                Pr[i] = Sscan[m0 + l];
                Pi[i] = Sscan[m0 + 65 + l];
                int n = 8 * w + i;
                qr[i] = cWSr[n]; qi[i] = cWSi[n];
            }
#pragma unroll
            for (int d = 1; d < 64; d <<= 1) {
#pragma unroll
                for (int i = 0; i < 8; i++) {
                    float tr = __shfl_up(Pr[i], (unsigned)d, 64);
                    float ti = __shfl_up(Pi[i], (unsigned)d, 64);
                    if (l >= d) {
                        Pr[i] = fmaf(qr[i], tr, fmaf(-qi[i], ti, Pr[i]));
                        Pi[i] = fmaf(qr[i], ti, fmaf( qi[i], tr, Pi[i]));
                    }
                }
                if (d < 32) {
#pragma unroll
                    for (int i = 0; i < 8; i++) {
                        float nr = fmaf(qr[i], qr[i], -(qi[i] * qi[i]));
                        float ni = 2.f * qr[i] * qi[i];
                        qr[i] = nr; qi[i] = ni;
                    }
                }
            }
            // G_s = P_{s-1}; E = 2Cw (x) G
#pragma unroll
            for (int i = 0; i < 8; i++) {
                float Gr = __shfl_up(Pr[i], 1u, 64);
                float Gi = __shfl_up(Pi[i], 1u, 64);
                if (l == 0) { Gr = 0.f; Gi = 0.f; }
                int n = 8 * w + i;
                float cr = c2R[n], ci = c2I[n];
                float er = fmaf(cr, Gr, -(ci * Gi));
                float ei = fmaf(cr, Gi,  (ci * Gr));
                int m0 = (16 * w + 2 * i) * 65;
                Sscan[m0 + l]      = er;
                Sscan[m0 + 65 + l] = ei;
            }
        }
        __syncthreads();   // (b)

        // E fragments: A rows = chunk 16w+l15, k = mode-comp
        s8v eh0, el0, eh1, el1;
        {
            float ev[16];
#pragma unroll
            for (int i = 0; i < 8; i++)
                ev[i] = Sscan[(8 * grp + i) * 65 + 16 * w + l15];
#pragma unroll
            for (int i = 0; i < 8; i++)
                ev[8 + i] = Sscan[(32 + 8 * grp + i) * 65 + 16 * w + l15];
#pragma unroll
            for (int i = 0; i < 8; i++) {
                unsigned short hh, ll;
                split2(ev[i], &hh, &ll);
                eh0[i] = (short)hh; el0[i] = (short)ll;
                split2(ev[8 + i], &hh, &ll);
                eh1[i] = (short)hh; el1[i] = (short)ll;
            }
        }
        __syncthreads();   // (c) — Sscan free for Y staging

        // Phase 3: Y = X*T + E*Wp -> stage into Sscan
#pragma unroll
        for (int tj = 0; tj < 4; tj++) {
            int row = tj * 16 + l15;
            int i0 = SWB(row, 8 * grp);
            int i1 = SWB(row, 32 + 8 * grp);
            s8v ph0 = *(const s8v*)&WpH[i0];
            s8v ph1 = *(const s8v*)&WpH[i1];
            f4v a = {0.f, 0.f, 0.f, 0.f};
            a = MFMA(xh0, tf[tj][0], a);
            a = MFMA(xh1, tf[tj][1], a);
            a = MFMA(xl0, tf[tj][0], a);
            a = MFMA(xl1, tf[tj][1], a);
            a = MFMA(eh0, ph0, a);
            a = MFMA(eh1, ph1, a);
            a = MFMA(el0, ph0, a);
            a = MFMA(el1, ph1, a);
#pragma unroll
            for (int r2 = 0; r2 < 4; r2++) {
                Sscan[(16 * w + 4 * grp + r2) * 65 + tj * 16 + l15] = a[r2];
            }
        }
        __syncthreads();   // (d) — Y tile complete in LDS

        // stream Y out: 4 x fully-coalesced 1KB/instr nontemporal float4 stores
        {
            float* yp = (float*)(wsp + (size_t)(b * Hc + h) * 8192);
#pragma unroll
            for (int i = 0; i < 4; i++) {
                int row = 16 * i + (tid >> 4);
                int col = 4 * (tid & 15);
                int base = row * 65 + col;
                f4v v;
                v.x = Sscan[base + 0];
                v.y = Sscan[base + 1];
                v.z = Sscan[base + 2];
                v.w = Sscan[base + 3];
                __builtin_nontemporal_store(v, (f4v*)yp + (i * 256 + tid));
            }
        }
        __syncthreads();   // (e) — Sscan free for next batch

        if (b < Bc - 1) { xh0 = nh0; xh1 = nh1; xl0 = nl0; xl1 = nl1; }
    }
}

extern "C" void kernel_launch(void* const* d_in, const int* in_sizes, int n_in,
                              void* d_out, int out_size, void* d_ws, size_t ws_size,
                              hipStream_t stream) {
    const float* x          = (const float*)d_in[0];
    const float* log_dt     = (const float*)d_in[1];
    const float* log_A_real = (const float*)d_in[2];
    const float* A_imag     = (const float*)d_in[3];
    const float* Cmat       = (const float*)d_in[4];
    const float* Dvec       = (const float*)d_in[5];
    float* out = (float*)d_out;

    const size_t need = (size_t)Bc * Hc * Lc * sizeof(float);   // 64 MiB
    if (ws_size < need) return;

    unsigned short* wsp = (unsigned short*)d_ws;

    // x [B][L][H] -> bf16 hi/lo planes per (b,h) 16KB block
    split_transpose<<<dim3(Hc / 64, Lc / 64, Bc), 256, 0, stream>>>(x, wsp);
    // fused SSM per h (all batches); writes yT fp32 over the same blocks
    s4d_mfma4<<<Hc, 256, 0, stream>>>(wsp, log_dt, log_A_real, A_imag, Cmat, Dvec);
    // yT [B][H][L] -> out [B][L][H]
    transpose_v4<<<dim3(Lc / 64, Hc / 64, Bc), 256, 0, stream>>>((const float*)d_ws, out, Hc, Lc);
}

// Round 7
// 104.551 us; speedup vs baseline: 1.1633x; 1.1633x over previous
//
#include <hip/hip_runtime.h>
#include <math.h>

#define Lc 4096
#define Hc 1024
#define Bc 4
#define NNc 32

typedef __attribute__((ext_vector_type(8))) short s8v;
typedef __attribute__((ext_vector_type(4))) float f4v;

// swizzled element index for [64][64] bf16 matrix (rows 128B): XOR 16B slot by row&7
#define SWB(r, e) ((((r) << 6) + (e)) ^ (((r) & 7) << 3))

__device__ inline unsigned short bf16_rne(float x) {
    unsigned u = __float_as_uint(x);
    unsigned r = (u + 0x7FFFu + ((u >> 16) & 1u)) >> 16;
    return (unsigned short)r;
}
__device__ inline void split2(float x, unsigned short* h, unsigned short* l) {
    unsigned short hb = bf16_rne(x);
    *h = hb;
    float hf = __uint_as_float(((unsigned)hb) << 16);
    *l = bf16_rne(x - hf);
}

// t1: x [B][L][H] fp32 -> per-(b,h) block (8192 shorts = 16KB): hi bf16[4096] in
// the first half; the rest is reserved for the fp32 yT overwrite.
__global__ __launch_bounds__(256) void split_transpose(const float* __restrict__ src,
                                                       unsigned short* __restrict__ dst) {
    __shared__ float tile[64][65];
    int b  = blockIdx.z;
    int h0 = blockIdx.x * 64;
    int l0 = blockIdx.y * 64;
    const float* s = src + (size_t)b * Lc * Hc;
    int tid = threadIdx.x;
#pragma unroll
    for (int it = 0; it < 4; it++) {
        int idx = tid + 256 * it;
        int r = idx >> 4, c4 = idx & 15;            // r = l-row, c4 = h-quad
        float4 v = *(const float4*)(s + (size_t)(l0 + r) * Hc + (h0 + 4 * c4));
        tile[r][4 * c4 + 0] = v.x;
        tile[r][4 * c4 + 1] = v.y;
        tile[r][4 * c4 + 2] = v.z;
        tile[r][4 * c4 + 3] = v.w;
    }
    __syncthreads();
#pragma unroll
    for (int it = 0; it < 8; it++) {
        int hh = it * 8 + (tid >> 5);               // h within tile
        int p  = tid & 31;                          // l-pair within tile
        float v0 = tile[2 * p + 0][hh];
        float v1 = tile[2 * p + 1][hh];
        unsigned hi = (unsigned)bf16_rne(v0) | ((unsigned)bf16_rne(v1) << 16);
        unsigned short* base = dst + ((size_t)(b * Hc + h0 + hh)) * 8192;
        *(unsigned*)(base + (l0 + 2 * p)) = hi;
    }
}

// Batched 64x64-tile transpose, float4 global accesses (yT -> out), nt stores.
__global__ __launch_bounds__(256) void transpose_v4(const float* __restrict__ src,
                                                    float* __restrict__ dst,
                                                    int R, int C) {
    __shared__ float tile[64][65];
    int b  = blockIdx.z;
    int c0 = blockIdx.x * 64;
    int r0 = blockIdx.y * 64;
    const float* s = src + (size_t)b * R * C;
    float*       d = dst + (size_t)b * R * C;
    int tid = threadIdx.x;
#pragma unroll
    for (int it = 0; it < 4; it++) {
        int idx = tid + 256 * it;
        int r = idx >> 4, c4 = idx & 15;
        float4 v = *(const float4*)(s + (size_t)(r0 + r) * C + (c0 + 4 * c4));
        tile[r][4 * c4 + 0] = v.x;
        tile[r][4 * c4 + 1] = v.y;
        tile[r][4 * c4 + 2] = v.z;
        tile[r][4 * c4 + 3] = v.w;
    }
    __syncthreads();
#pragma unroll
    for (int it = 0; it < 4; it++) {
        int idx = tid + 256 * it;
        int cc = idx >> 4, r4 = idx & 15;
        f4v v;
        v.x = tile[4 * r4 + 0][cc];
        v.y = tile[4 * r4 + 1][cc];
        v.z = tile[4 * r4 + 2][cc];
        v.w = tile[4 * r4 + 3][cc];
        __builtin_nontemporal_store(v, (f4v*)(d + (size_t)(c0 + cc) * R + (r0 + 4 * r4)));
    }
}

#define MFMA(a, b, c) __builtin_amdgcn_mfma_f32_16x16x32_bf16((a), (b), (c), 0, 0, 0)

// One block per h; 4 batches. ws holds x hi bf16 plane per (b,h) 16KB block;
// yT fp32 overwrites the same block (LDS-staged coalesced plain stores).
__global__ __launch_bounds__(256, 4) void s4d_mfma5(
    unsigned short* __restrict__ wsp,
    const float* __restrict__ log_dt,
    const float* __restrict__ log_A_real,
    const float* __restrict__ A_imag,
    const float* __restrict__ Cmat,
    const float* __restrict__ Dvec)
{
    __shared__ __align__(16) unsigned short WtH[4096];   // S = X*Wrev (hi)
    __shared__ __align__(16) unsigned short WpH[4096];   // carry powers (hi)
    __shared__ float Sscan[64 * 65];   // [mode-comp][chunk]; Kpart scratch; Y staging
    __shared__ float Ktap[64];
    __shared__ float cAr[NNc], cAi[NNc], c2R[NNc], c2I[NNc], cWSr[NNc], cWSi[NNc];

    const int tid = threadIdx.x;
    const int h   = blockIdx.x;
    const int w   = tid >> 6;
    const int l   = tid & 63;
    const int l15 = l & 15;
    const int grp = l >> 4;
    const int rowoff = (16 * w + l15) * 64;

    // early X frag load for b=0 (hides under table generation)
    s8v xh0, xh1;
    {
        const unsigned short* xb = wsp + (size_t)h * 8192;
        xh0 = *(const s8v*)(xb + rowoff + 8 * grp);
        xh1 = *(const s8v*)(xb + rowoff + 32 + 8 * grp);
    }

    // ---- per-mode constants (PRECISE: w^64 errors compound x63 in the scan) ----
    if (tid < NNc) {
        int n = tid;
        float dtv = expf(log_dt[h]);
        float Ar = -expf(log_A_real[h * NNc + n]);
        float Ai = A_imag[h * NNc + n];
        float ar = Ar * dtv, ai = Ai * dtv;
        cAr[n] = ar; cAi[n] = ai;
        float er = expf(ar), sn, cs;
        sincosf(ai, &sn, &cs);
        float numr = er * cs - 1.f, numi = er * sn;
        float inv = 1.f / (Ar * Ar + Ai * Ai);
        float fr = (numr * Ar + numi * Ai) * inv;
        float fi = (numi * Ar - numr * Ai) * inv;
        float Ccr = Cmat[(h * NNc + n) * 2 + 0];
        float Cci = Cmat[(h * NNc + n) * 2 + 1];
        c2R[n] = 2.f * (Ccr * fr - Cci * fi);
        c2I[n] = 2.f * (Ccr * fi + Cci * fr);
        float e64 = expf(64.f * ar), s64, c64;
        sincosf(64.f * ai, &s64, &c64);
        cWSr[n] = e64 * c64; cWSi[n] = e64 * s64;   // w^64
    }
    __syncthreads();

    // ---- Kpart (into Sscan scratch) + Wt + Wp generation (fast intrinsics) ----
    {
        int p = tid >> 2, q = tid & 3;
        float acc = 0.f;
#pragma unroll
        for (int i = 0; i < 8; i++) {
            int n = 8 * q + i;
            float fp = (float)p;
            float e = __expf(cAr[n] * fp);
            float sn = __sinf(cAi[n] * fp), cs = __cosf(cAi[n] * fp);
            acc += e * (c2R[n] * cs - c2I[n] * sn);
        }
        Sscan[p * 4 + q] = acc;
    }
#pragma unroll
    for (int m = 0; m < 2; m++) {
        int u = tid + 256 * m;
        int r = u >> 3, jc = u & 7;
        {   // Wt row r = out mode-comp: w_n^{63-j} (hi only)
            int n = r >> 1, im = r & 1;
            s8v hv;
#pragma unroll
            for (int i = 0; i < 8; i++) {
                float p = (float)(63 - (jc * 8 + i));
                float e = __expf(cAr[n] * p);
                float sn = __sinf(cAi[n] * p), cs = __cosf(cAi[n] * p);
                hv[i] = (short)bf16_rne(e * (im ? sn : cs));
            }
            *(s8v*)&WtH[SWB(r, jc * 8)] = hv;
        }
        {   // Wp row r = t: col c: Re(w^{t+1}) / -Im(w^{t+1})  (hi only)
            float p = (float)(r + 1);
            s8v hv;
#pragma unroll
            for (int i = 0; i < 8; i++) {
                int c = jc * 8 + i;
                int n = c >> 1;
                float e = __expf(cAr[n] * p);
                float sn = __sinf(cAi[n] * p), cs = __cosf(cAi[n] * p);
                hv[i] = (short)bf16_rne(e * ((c & 1) ? -sn : cs));
            }
            *(s8v*)&WpH[SWB(r, jc * 8)] = hv;
        }
    }
    __syncthreads();

    if (tid < 64) {
        float k = Sscan[tid * 4] + Sscan[tid * 4 + 1] + Sscan[tid * 4 + 2] + Sscan[tid * 4 + 3];
        if (tid == 0) k += Dvec[h];
        Ktap[tid] = k;
    }
    __syncthreads();

    // ---- Toeplitz B-fragments: batch-invariant -> registers (8 x s8v) ----
    s8v tf[4][2];
#pragma unroll
    for (int tj = 0; tj < 4; tj++) {
        int row = tj * 16 + l15;
#pragma unroll
        for (int hf = 0; hf < 2; hf++) {
            int kb = 32 * hf + 8 * grp;
            s8v v;
#pragma unroll
            for (int i = 0; i < 8; i++) {
                int idx = row - kb - i;
                int ic = idx < 0 ? 0 : idx;
                float kv = Ktap[ic];
                v[i] = (short)bf16_rne(idx < 0 ? 0.f : kv);
            }
            tf[tj][hf] = v;
        }
    }

    // ---- batch loop ----
#pragma unroll
    for (int b = 0; b < Bc; b++) {
        // prefetch next batch's X fragments
        s8v nh0, nh1;
        if (b < Bc - 1) {
            const unsigned short* xb = wsp + (size_t)((b + 1) * Hc + h) * 8192;
            nh0 = *(const s8v*)(xb + rowoff + 8 * grp);
            nh1 = *(const s8v*)(xb + rowoff + 32 + 8 * grp);
        }

        // Phase 1: S = X * Wrev. D rows = chunk s, cols = mode-comp m.
        f4v acc[4];
#pragma unroll
        for (int tj = 0; tj < 4; tj++) {
            int row = tj * 16 + l15;
            int i0 = SWB(row, 8 * grp);
            int i1 = SWB(row, 32 + 8 * grp);
            s8v bh0 = *(const s8v*)&WtH[i0];
            s8v bh1 = *(const s8v*)&WtH[i1];
            f4v a = {0.f, 0.f, 0.f, 0.f};
            a = MFMA(xh0, bh0, a);
            a = MFMA(xh1, bh1, a);
            acc[tj] = a;
        }
        // store S transposed: Sscan[m][s]
#pragma unroll
        for (int tj = 0; tj < 4; tj++) {
#pragma unroll
            for (int r2 = 0; r2 < 4; r2++) {
                Sscan[(tj * 16 + l15) * 65 + 16 * w + 4 * grp + r2] = acc[tj][r2];
            }
        }
        __syncthreads();   // (a)

        // ---- wave-parallel Kogge-Stone scan: wave w owns modes 8w..8w+7, lane = chunk ----
        {
            float Pr[8], Pi[8], qr[8], qi[8];
#pragma unroll
            for (int i = 0; i < 8; i++) {
                int m0 = (16 * w + 2 * i) * 65;
                Pr[i] = Sscan[m0 + l];
                Pi[i] = Sscan[m0 + 65 + l];
                int n = 8 * w + i;
                qr[i] = cWSr[n]; qi[i] = cWSi[n];
            }
#pragma unroll
            for (int d = 1; d < 64; d <<= 1) {
#pragma unroll
                for (int i = 0; i < 8; i++) {
                    float tr = __shfl_up(Pr[i], (unsigned)d, 64);
                    float ti = __shfl_up(Pi[i], (unsigned)d, 64);
                    if (l >= d) {
                        Pr[i] = fmaf(qr[i], tr, fmaf(-qi[i], ti, Pr[i]));
                        Pi[i] = fmaf(qr[i], ti, fmaf( qi[i], tr, Pi[i]));
                    }
                }
                if (d < 32) {
#pragma unroll
                    for (int i = 0; i < 8; i++) {
                        float nr = fmaf(qr[i], qr[i], -(qi[i] * qi[i]));
                        float ni = 2.f * qr[i] * qi[i];
                        qr[i] = nr; qi[i] = ni;
                    }
                }
            }
            // G_s = P_{s-1}; E = 2Cw (x) G
#pragma unroll
            for (int i = 0; i < 8; i++) {
                float Gr = __shfl_up(Pr[i], 1u, 64);
                float Gi = __shfl_up(Pi[i], 1u, 64);
                if (l == 0) { Gr = 0.f; Gi = 0.f; }
                int n = 8 * w + i;
                float cr = c2R[n], ci = c2I[n];
                float er = fmaf(cr, Gr, -(ci * Gi));
                float ei = fmaf(cr, Gi,  (ci * Gr));
                int m0 = (16 * w + 2 * i) * 65;
                Sscan[m0 + l]      = er;
                Sscan[m0 + 65 + l] = ei;
            }
        }
        __syncthreads();   // (b)

        // E fragments: A rows = chunk 16w+l15, k = mode-comp
        s8v eh0, el0, eh1, el1;
        {
            float ev[16];
#pragma unroll
            for (int i = 0; i < 8; i++)
                ev[i] = Sscan[(8 * grp + i) * 65 + 16 * w + l15];
#pragma unroll
            for (int i = 0; i < 8; i++)
                ev[8 + i] = Sscan[(32 + 8 * grp + i) * 65 + 16 * w + l15];
#pragma unroll
            for (int i = 0; i < 8; i++) {
                unsigned short hh, ll;
                split2(ev[i], &hh, &ll);
                eh0[i] = (short)hh; el0[i] = (short)ll;
                split2(ev[8 + i], &hh, &ll);
                eh1[i] = (short)hh; el1[i] = (short)ll;
            }
        }
        __syncthreads();   // (c) — Sscan free for Y staging

        // Phase 3: Y = X*T + E*Wp -> stage into Sscan
#pragma unroll
        for (int tj = 0; tj < 4; tj++) {
            int row = tj * 16 + l15;
            int i0 = SWB(row, 8 * grp);
            int i1 = SWB(row, 32 + 8 * grp);
            s8v ph0 = *(const s8v*)&WpH[i0];
            s8v ph1 = *(const s8v*)&WpH[i1];
            f4v a = {0.f, 0.f, 0.f, 0.f};
            a = MFMA(xh0, tf[tj][0], a);
            a = MFMA(xh1, tf[tj][1], a);
            a = MFMA(eh0, ph0, a);
            a = MFMA(eh1, ph1, a);
            a = MFMA(el0, ph0, a);
            a = MFMA(el1, ph1, a);
#pragma unroll
            for (int r2 = 0; r2 < 4; r2++) {
                Sscan[(16 * w + 4 * grp + r2) * 65 + tj * 16 + l15] = a[r2];
            }
        }
        __syncthreads();   // (d) — Y tile complete in LDS

        // stream Y out: 4 x fully-coalesced 1KB/instr plain float4 stores
        {
            float* yp = (float*)(wsp + (size_t)(b * Hc + h) * 8192);
#pragma unroll
            for (int i = 0; i < 4; i++) {
                int row = 16 * i + (tid >> 4);
                int col = 4 * (tid & 15);
                int base = row * 65 + col;
                f4v v;
                v.x = Sscan[base + 0];
                v.y = Sscan[base + 1];
                v.z = Sscan[base + 2];
                v.w = Sscan[base + 3];
                *((f4v*)yp + (i * 256 + tid)) = v;
            }
        }
        __syncthreads();   // (e) — Sscan free for next batch

        if (b < Bc - 1) { xh0 = nh0; xh1 = nh1; }
    }
}

extern "C" void kernel_launch(void* const* d_in, const int* in_sizes, int n_in,
                              void* d_out, int out_size, void* d_ws, size_t ws_size,
                              hipStream_t stream) {
    const float* x          = (const float*)d_in[0];
    const float* log_dt     = (const float*)d_in[1];
    const float* log_A_real = (const float*)d_in[2];
    const float* A_imag     = (const float*)d_in[3];
    const float* Cmat       = (const float*)d_in[4];
    const float* Dvec       = (const float*)d_in[5];
    float* out = (float*)d_out;

    const size_t need = (size_t)Bc * Hc * Lc * sizeof(float);   // 64 MiB
    if (ws_size < need) return;

    unsigned short* wsp = (unsigned short*)d_ws;

    // x [B][L][H] -> bf16 hi plane per (b,h) 16KB block
    split_transpose<<<dim3(Hc / 64, Lc / 64, Bc), 256, 0, stream>>>(x, wsp);
    // fused SSM per h (all batches); writes yT fp32 over the same blocks
    s4d_mfma5<<<Hc, 256, 0, stream>>>(wsp, log_dt, log_A_real, A_imag, Cmat, Dvec);
    // yT [B][H][L] -> out [B][L][H]
    transpose_v4<<<dim3(Lc / 64, Hc / 64, Bc), 256, 0, stream>>>((const float*)d_ws, out, Hc, Lc);
}